// Round 6
// baseline (2033.674 us; speedup 1.0000x reference)
//
#include <hip/hip_runtime.h>
#include <hip/hip_bf16.h>
#include <hip/hip_fp16.h>
#include <math.h>

// NODE_DIM=3, EMBED=16
#define ND 3
#define EM 16
#define BK 8             // log2(nodes per dst-bucket)
#define BN 256           // nodes per dst-bucket
#define ACCP 17          // padded LDS accumulator stride
#define HNB 2048         // max dst-buckets (N=500000 -> NB=1954)
#define MAXSL 16         // max src-slices (slice = src >> 16)

typedef _Float16 f16;
typedef _Float16 f16x8 __attribute__((ext_vector_type(8)));

__device__ __forceinline__ float sp(float x) {
    // jax.nn.softplus = max(x,0) + log1p(exp(-|x|))
    return fmaxf(x, 0.0f) + log1pf(expf(-fabsf(x)));
}

// ---- bucket pipeline -------------------------------------------------------

__global__ __launch_bounds__(1024) void zero_gcur(int* __restrict__ gcur, int NB) {
    int i = blockIdx.x * 1024 + threadIdx.x;
    if (i < NB) gcur[i] = 0;
}

// Histogram of dst-buckets. 4096 edges per WG.
__global__ __launch_bounds__(256) void hist_kernel(
    const int* __restrict__ ei, int* __restrict__ gcur, int E, int NB)
{
    __shared__ int h[HNB];
    int t = threadIdx.x;
    for (int i = t; i < NB; i += 256) h[i] = 0;
    __syncthreads();
    int base = blockIdx.x * 4096;
#pragma unroll
    for (int i = 0; i < 16; i++) {
        int e = base + i * 256 + t;
        if (e < E) atomicAdd(&h[ei[(size_t)E + e] >> BK], 1);
    }
    __syncthreads();
    for (int i = t; i < NB; i += 256) if (h[i]) atomicAdd(&gcur[i], h[i]);
}

// Exclusive scan of bucket counts -> bbase[NB+1]; reset gcur (NB <= 2048).
__global__ __launch_bounds__(1024) void scan_kernel(
    int* __restrict__ gcur, int* __restrict__ bbase, int NB, int E)
{
    __shared__ int sd[1024];
    int t = threadIdx.x;
    int i0 = 2 * t, i1 = 2 * t + 1;
    int v0 = (i0 < NB) ? gcur[i0] : 0;
    int v1 = (i1 < NB) ? gcur[i1] : 0;
    int pv = v0 + v1;
    sd[t] = pv;
    __syncthreads();
    for (int off = 1; off < 1024; off <<= 1) {
        int a = (t >= off) ? sd[t - off] : 0;
        __syncthreads();
        sd[t] += a;
        __syncthreads();
    }
    int base = sd[t] - pv;  // exclusive prefix of this pair
    if (i0 < NB) { bbase[i0] = base;      gcur[i0] = 0; }
    if (i1 < NB) { bbase[i1] = base + v0; gcur[i1] = 0; }
    if (t == 0) bbase[NB] = E;
}

// Multisplit by dst-bucket: packed records (src<<BK | dst&(BN-1)) -> rec.
__global__ __launch_bounds__(256) void pass2_kernel(
    const int* __restrict__ ei, const int* __restrict__ bbase,
    int* __restrict__ gcur, unsigned* __restrict__ rec, int E, int NB)
{
    __shared__ int h[HNB];
    __shared__ int gslot[HNB];
    int t = threadIdx.x;
    for (int i = t; i < NB; i += 256) h[i] = 0;
    __syncthreads();
    int base = blockIdx.x * 4096;
    unsigned rr[16]; int bb[16];
#pragma unroll
    for (int i = 0; i < 16; i++) {
        int e = base + i * 256 + t;
        if (e < E) {
            int s = ei[e];
            int d = ei[(size_t)E + e];
            bb[i] = d >> BK;
            rr[i] = ((unsigned)s << BK) | (unsigned)(d & (BN - 1));
            atomicAdd(&h[bb[i]], 1);
        } else bb[i] = -1;
    }
    __syncthreads();
    for (int i = t; i < NB; i += 256) {
        int c = h[i];
        if (c > 0) gslot[i] = bbase[i] + atomicAdd(&gcur[i], c);
        h[i] = 0;  // reuse as local cursor
    }
    __syncthreads();
#pragma unroll
    for (int i = 0; i < 16; i++) {
        if (bb[i] >= 0) {
            int r = atomicAdd(&h[bb[i]], 1);
            rec[gslot[bb[i]] + r] = rr[i];
        }
    }
}

// Per-bucket: (a) counting-sort records by src-slice (rec -> rec2, offsets soff),
// (b) edge weight w per record -> wrec (fp16, aligned with rec2),
// (c) weighted degree + count -> dinv = rsqrt(1+sum_w), rcnt = 1/(1+cnt).
__global__ __launch_bounds__(256) void sortdeg_kernel(
    const unsigned* __restrict__ rec, const int* __restrict__ bbase,
    const float* __restrict__ pos,
    unsigned* __restrict__ rec2, f16* __restrict__ wrec, int* __restrict__ soff,
    float* __restrict__ dinv, float* __restrict__ rcnt, int N, int NSL)
{
    __shared__ float posL[BN * 3];
    __shared__ float ws[BN];
    __shared__ int cs[BN];
    __shared__ int hcnt[MAXSL];
    __shared__ int hoff[MAXSL + 1];
    int t = threadIdx.x;
    int b = blockIdx.x;
    int nb0 = b << BK;
    if (t < MAXSL) hcnt[t] = 0;
    for (int i = t; i < BN; i += 256) {
        int n = nb0 + i;
        float px = 0, py = 0, pz = 0;
        if (n < N) {
            px = pos[3 * (size_t)n + 0];
            py = pos[3 * (size_t)n + 1];
            pz = pos[3 * (size_t)n + 2];
        }
        posL[i * 3 + 0] = px; posL[i * 3 + 1] = py; posL[i * 3 + 2] = pz;
        ws[i] = 0.0f; cs[i] = 0;
    }
    __syncthreads();
    int rb = bbase[b], re = bbase[b + 1];
    for (int j = rb + t; j < re; j += 256)
        atomicAdd(&hcnt[(rec[j] >> BK) >> 16], 1);
    __syncthreads();
    if (t == 0) {
        int run = rb;
        for (int s2 = 0; s2 < NSL; s2++) { hoff[s2] = run; run += hcnt[s2]; }
        hoff[NSL] = run;   // == re
    }
    __syncthreads();
    if (t <= NSL) soff[(size_t)b * (NSL + 1) + t] = hoff[t];
    if (t < MAXSL) hcnt[t] = 0;   // reuse as cursors
    __syncthreads();
    for (int j = rb + t; j < re; j += 256) {
        unsigned r = rec[j];
        int s = r >> BK;
        int dl = r & (BN - 1);
        int sl = s >> 16;
        float dx = posL[dl * 3 + 0] - pos[3 * (size_t)s + 0];
        float dy = posL[dl * 3 + 1] - pos[3 * (size_t)s + 1];
        float dz = posL[dl * 3 + 2] - pos[3 * (size_t)s + 2];
        float w = sqrtf(fmaf(dx, dx, fmaf(dy, dy, dz * dz)));
        int p = hoff[sl] + atomicAdd(&hcnt[sl], 1);
        rec2[p] = r;
        wrec[p] = (f16)w;
        atomicAdd(&ws[dl], w);
        atomicAdd(&cs[dl], 1);
    }
    __syncthreads();
    for (int i = t; i < BN; i += 256) {
        int n = nb0 + i;
        if (n < N) {
            dinv[n] = rsqrtf(1.0f + ws[i]);
            rcnt[n] = 1.0f / (float)(1 + cs[i]);
        }
    }
}

// x0 = sp(pos@Wi+bi); xwA = fp16( dinv[n] * (x0 @ W_g1) )  (pre-scaled by dinv[src])
__global__ __launch_bounds__(256) void node_init(
    const float* __restrict__ pos,
    const float* __restrict__ W_init, const float* __restrict__ b_init,
    const float* __restrict__ W_g1, const float* __restrict__ dinv,
    f16* __restrict__ xw, int N)
{
    __shared__ float sWi[ND * EM];
    __shared__ float sbi[EM];
    __shared__ float sW1[EM * EM];
    int t = threadIdx.x;
    if (t < ND * EM) sWi[t] = W_init[t];
    if (t < EM)      sbi[t] = b_init[t];
    sW1[t] = W_g1[t];
    __syncthreads();

    int n = blockIdx.x * 256 + t;
    if (n >= N) return;

    float p0 = pos[3 * (size_t)n + 0];
    float p1 = pos[3 * (size_t)n + 1];
    float p2 = pos[3 * (size_t)n + 2];

    float x0[EM];
#pragma unroll
    for (int j = 0; j < EM; j++) {
        float h = fmaf(p0, sWi[0 * EM + j],
                  fmaf(p1, sWi[1 * EM + j],
                  fmaf(p2, sWi[2 * EM + j], sbi[j])));
        x0[j] = sp(h);
    }
    float di = dinv[n];
    f16x8 h0, h1;
#pragma unroll
    for (int k = 0; k < EM; k++) {
        float a = 0.0f;
#pragma unroll
        for (int j = 0; j < EM; j++) a = fmaf(x0[j], sW1[j * EM + k], a);
        float v = a * di;
        if (k < 8) h0[k] = (f16)v; else h1[k - 8] = (f16)v;
    }
    f16x8* xo = (f16x8*)(xw + (size_t)n * EM);
    xo[0] = h0; xo[1] = h1;
}

// One src-slice pass of a GCN layer. Processes only records with src-slice s
// (xin rows for slice s span 2 MB -> L2-resident, replicated in every XCD).
// s==0: zero LDS acc; s>0: preload partial from accbuf. !last: write partial.
// last: fused epilogue. mode1: xout=fp16(dinv*(sp(mean+bias)@W)); mode2: heads.
__global__ __launch_bounds__(256, 8) void conv_pass(
    const unsigned* __restrict__ rec2, const f16* __restrict__ wrec,
    const int* __restrict__ soff, float* __restrict__ accbuf,
    const f16* __restrict__ xin,
    const float* __restrict__ dinv, const float* __restrict__ rcnt,
    const float* __restrict__ bias, const float* __restrict__ W,
    const float* __restrict__ W_p1, const float* __restrict__ b_p1,
    const float* __restrict__ W_p2, const float* __restrict__ b_p2,
    const float* __restrict__ sig,
    f16* __restrict__ xoutH, float* __restrict__ outF,
    int N, int NSL, int s, int last, int mode)
{
    __shared__ float acc[BN * ACCP];    // 17.4 KB
    __shared__ float dinvL[BN];
    __shared__ float sW[EM * EM];       // W (mode1) or W_p1 (mode2), last pass only
    __shared__ float sb[EM];
    __shared__ float sbp1[EM];
    __shared__ float sP2[EM * ND];
    __shared__ float sbp2[ND];

    int t = threadIdx.x;
    int b = blockIdx.x;
    int nb0 = b << BK;
    if (last) {
        if (mode == 1) {
            sW[t] = W[t];
        } else {
            sW[t] = W_p1[t];
            if (t < EM)      sbp1[t] = b_p1[t];
            if (t < EM * ND) sP2[t] = W_p2[t];
            if (t < ND)      sbp2[t] = b_p2[t];
        }
        if (t < EM) sb[t] = bias[t];
    }
    for (int i = t; i < BN; i += 256) {
        int n = nb0 + i;
        dinvL[i] = (n < N) ? dinv[n] : 0.0f;
    }
    float* ab = accbuf + (size_t)b * (BN * EM);
    if (s == 0) {
        for (int idx = t; idx < BN * EM; idx += 256)
            acc[(idx >> 4) * ACCP + (idx & 15)] = 0.0f;
    } else {
        for (int idx = t; idx < BN * EM; idx += 256)
            acc[(idx >> 4) * ACCP + (idx & 15)] = ab[idx];
    }
    __syncthreads();

    int base = b * (NSL + 1) + s;
    int s0 = soff[base], s1 = soff[base + 1];
    int sub = t >> 4, c = t & 15;
    int j = s0 + sub;
    // unrolled-by-8: 8 independent (L2-resident) xin lines in flight per slot
    for (; j + 112 < s1; j += 128) {
        unsigned r[8]; float wv[8];
#pragma unroll
        for (int u = 0; u < 8; u++) { r[u] = rec2[j + 16 * u]; wv[u] = (float)wrec[j + 16 * u]; }
        float xv[8];
#pragma unroll
        for (int u = 0; u < 8; u++) xv[u] = (float)xin[((size_t)(r[u] >> BK) << 4) + c];
#pragma unroll
        for (int u = 0; u < 8; u++) {
            int dl = r[u] & (BN - 1);
            atomicAdd(&acc[dl * ACCP + c], wv[u] * dinvL[dl] * xv[u]);
        }
    }
    for (; j < s1; j += 16) {
        unsigned r = rec2[j];
        float w = (float)wrec[j];
        int dl = r & (BN - 1);
        float xv = (float)xin[((size_t)(r >> BK) << 4) + c];
        atomicAdd(&acc[dl * ACCP + c], w * dinvL[dl] * xv);
    }
    __syncthreads();

    if (!last) {
        for (int idx = t; idx < BN * EM; idx += 256)
            ab[idx] = acc[(idx >> 4) * ACCP + (idx & 15)];
        return;
    }

    // fused epilogue (last pass only)
    int g = t >> 4;
    for (int i = g; i < BN; i += 16) {
        int n = nb0 + i;
        float xv = 0.0f;
        if (n < N) {
            float self = dinvL[i] * (float)xin[((size_t)n << 4) + c];
            xv = sp(fmaf(acc[i * ACCP + c] + self, rcnt[n], sb[c]));
        }
        acc[i * ACCP + c] = xv;   // same-wave 16-lane group: write then read (lockstep)
        if (n < N) {
            if (mode == 1) {
                float o = 0.0f;
#pragma unroll
                for (int jj = 0; jj < EM; jj++)
                    o = fmaf(acc[i * ACCP + jj], sW[jj * EM + c], o);
                xoutH[((size_t)n << 4) + c] = (f16)(dinvL[i] * o);
            } else {
                float a = sbp1[c];
#pragma unroll
                for (int jj = 0; jj < EM; jj++)
                    a = fmaf(acc[i * ACCP + jj], sW[jj * EM + c], a);
                float y = sp(a);
                acc[i * ACCP + c] = y;   // lockstep again
                if (c < ND) {
                    float o = sbp2[c];
#pragma unroll
                    for (int jj = 0; jj < EM; jj++)
                        o = fmaf(acc[i * ACCP + jj], sP2[jj * ND + c], o);
                    outF[(size_t)n * ND + c] = o / sig[n];
                }
            }
        }
    }
}

extern "C" void kernel_launch(void* const* d_in, const int* in_sizes, int n_in,
                              void* d_out, int out_size, void* d_ws, size_t ws_size,
                              hipStream_t stream) {
    const float* pos    = (const float*)d_in[0];
    const float* sig    = (const float*)d_in[1];
    const int*   ei     = (const int*)d_in[2];
    const float* W_init = (const float*)d_in[4];
    const float* b_init = (const float*)d_in[5];
    const float* W_g1   = (const float*)d_in[6];
    const float* b_g1   = (const float*)d_in[7];
    const float* W_g2   = (const float*)d_in[8];
    const float* b_g2   = (const float*)d_in[9];
    const float* W_p1   = (const float*)d_in[10];
    const float* b_p1   = (const float*)d_in[11];
    const float* W_p2   = (const float*)d_in[12];
    const float* b_p2   = (const float*)d_in[13];
    float* out = (float*)d_out;

    int N = in_sizes[0] / ND;
    int E = in_sizes[2] / 2;
    int NB = (N + BN - 1) >> BK;          // 1954 for N=500000
    int NSL = (N + 65535) >> 16;          // src-slices of 65536 nodes (8 here)
    size_t Ns = (size_t)N, Es = (size_t)E;

    // ws layout, 64B-aligned chunks. Region R holds rec (dead after sortdeg)
    // then is reused as accbuf (NB*256*16 fp32).
    char* wsb = (char*)d_ws;
    size_t cur = 0;
    auto alloc = [&](size_t bytes) -> void* {
        void* p = wsb + cur; cur += (bytes + 63) & ~(size_t)63; return p;
    };
    size_t accElems = (size_t)NB * BN * EM;
    size_t regionBytes = (Es > accElems ? Es : accElems) * 4;
    unsigned* rec = (unsigned*)alloc(regionBytes);
    float* accbuf = (float*)rec;
    unsigned* rec2 = (unsigned*)alloc(Es * 4);
    f16* wrec = (f16*)alloc(Es * 2);
    int* soff = (int*)alloc((size_t)NB * (NSL + 1) * 4 + 64);
    int* bbase = (int*)alloc(((size_t)NB + 1) * 4);
    int* gcur  = (int*)alloc((size_t)NB * 4);
    float* dinv = (float*)alloc(Ns * 4);
    float* rcnt = (float*)alloc(Ns * 4);
    f16* xwA = (f16*)alloc(Ns * EM * 2);
    f16* xwB = (f16*)alloc(Ns * EM * 2);

    int nbN = (N + 255) / 256;
    int nbE4 = (E + 4095) / 4096;

    zero_gcur<<<(NB + 1023) / 1024, 1024, 0, stream>>>(gcur, NB);
    hist_kernel<<<nbE4, 256, 0, stream>>>(ei, gcur, E, NB);
    scan_kernel<<<1, 1024, 0, stream>>>(gcur, bbase, NB, E);
    pass2_kernel<<<nbE4, 256, 0, stream>>>(ei, bbase, gcur, rec, E, NB);
    sortdeg_kernel<<<NB, 256, 0, stream>>>(rec, bbase, pos, rec2, wrec, soff,
                                           dinv, rcnt, N, NSL);
    node_init<<<nbN, 256, 0, stream>>>(pos, W_init, b_init, W_g1, dinv, xwA, N);
    for (int s = 0; s < NSL; s++)
        conv_pass<<<NB, 256, 0, stream>>>(rec2, wrec, soff, accbuf, xwA, dinv, rcnt,
                                          b_g1, W_g2, W_p1, b_p1, W_p2, b_p2, sig,
                                          xwB, out, N, NSL, s, s == NSL - 1, 1);
    for (int s = 0; s < NSL; s++)
        conv_pass<<<NB, 256, 0, stream>>>(rec2, wrec, soff, accbuf, xwB, dinv, rcnt,
                                          b_g2, W_g2, W_p1, b_p1, W_p2, b_p2, sig,
                                          xwB, out, N, NSL, s, s == NSL - 1, 2);
}

// Round 7
// 2001.103 us; speedup vs baseline: 1.0163x; 1.0163x over previous
//
#include <hip/hip_runtime.h>
#include <hip/hip_bf16.h>
#include <hip/hip_fp16.h>
#include <math.h>

// NODE_DIM=3, EMBED=16
#define ND 3
#define EM 16
#define BK 8             // log2(nodes per dst-bucket)
#define BN 256           // nodes per dst-bucket
#define ACCP 17          // padded LDS accumulator stride
#define HNB 2048         // max dst-buckets (N=500000 -> NB=1954)
#define SLK 12           // micro-slice key shift: slice = src >> 12 (4096 nodes)
#define MAXSL 128        // max micro-slices (N=500000 -> 123)

typedef _Float16 f16;
typedef _Float16 f16x8 __attribute__((ext_vector_type(8)));

__device__ __forceinline__ float sp(float x) {
    // jax.nn.softplus = max(x,0) + log1p(exp(-|x|))
    return fmaxf(x, 0.0f) + log1pf(expf(-fabsf(x)));
}

// ---- bucket pipeline -------------------------------------------------------

__global__ __launch_bounds__(1024) void zero_gcur(int* __restrict__ gcur, int NB) {
    int i = blockIdx.x * 1024 + threadIdx.x;
    if (i < NB) gcur[i] = 0;
}

// Histogram of dst-buckets. 4096 edges per WG.
__global__ __launch_bounds__(256) void hist_kernel(
    const int* __restrict__ ei, int* __restrict__ gcur, int E, int NB)
{
    __shared__ int h[HNB];
    int t = threadIdx.x;
    for (int i = t; i < NB; i += 256) h[i] = 0;
    __syncthreads();
    int base = blockIdx.x * 4096;
#pragma unroll
    for (int i = 0; i < 16; i++) {
        int e = base + i * 256 + t;
        if (e < E) atomicAdd(&h[ei[(size_t)E + e] >> BK], 1);
    }
    __syncthreads();
    for (int i = t; i < NB; i += 256) if (h[i]) atomicAdd(&gcur[i], h[i]);
}

// Exclusive scan of bucket counts -> bbase[NB+1]; reset gcur (NB <= 2048).
__global__ __launch_bounds__(1024) void scan_kernel(
    int* __restrict__ gcur, int* __restrict__ bbase, int NB, int E)
{
    __shared__ int sd[1024];
    int t = threadIdx.x;
    int i0 = 2 * t, i1 = 2 * t + 1;
    int v0 = (i0 < NB) ? gcur[i0] : 0;
    int v1 = (i1 < NB) ? gcur[i1] : 0;
    int pv = v0 + v1;
    sd[t] = pv;
    __syncthreads();
    for (int off = 1; off < 1024; off <<= 1) {
        int a = (t >= off) ? sd[t - off] : 0;
        __syncthreads();
        sd[t] += a;
        __syncthreads();
    }
    int base = sd[t] - pv;  // exclusive prefix of this pair
    if (i0 < NB) { bbase[i0] = base;      gcur[i0] = 0; }
    if (i1 < NB) { bbase[i1] = base + v0; gcur[i1] = 0; }
    if (t == 0) bbase[NB] = E;
}

// Multisplit by dst-bucket: packed records (src<<BK | dst&(BN-1)) -> rec.
__global__ __launch_bounds__(256) void pass2_kernel(
    const int* __restrict__ ei, const int* __restrict__ bbase,
    int* __restrict__ gcur, unsigned* __restrict__ rec, int E, int NB)
{
    __shared__ int h[HNB];
    __shared__ int gslot[HNB];
    int t = threadIdx.x;
    for (int i = t; i < NB; i += 256) h[i] = 0;
    __syncthreads();
    int base = blockIdx.x * 4096;
    unsigned rr[16]; int bb[16];
#pragma unroll
    for (int i = 0; i < 16; i++) {
        int e = base + i * 256 + t;
        if (e < E) {
            int s = ei[e];
            int d = ei[(size_t)E + e];
            bb[i] = d >> BK;
            rr[i] = ((unsigned)s << BK) | (unsigned)(d & (BN - 1));
            atomicAdd(&h[bb[i]], 1);
        } else bb[i] = -1;
    }
    __syncthreads();
    for (int i = t; i < NB; i += 256) {
        int c = h[i];
        if (c > 0) gslot[i] = bbase[i] + atomicAdd(&gcur[i], c);
        h[i] = 0;  // reuse as local cursor
    }
    __syncthreads();
#pragma unroll
    for (int i = 0; i < 16; i++) {
        if (bb[i] >= 0) {
            int r = atomicAdd(&h[bb[i]], 1);
            rec[gslot[bb[i]] + r] = rr[i];
        }
    }
}

// Per-bucket: counting-sort records by src micro-slice (rec -> rec2, w -> wrec),
// plus weighted degree + count -> dinv = rsqrt(1+sum_w), rcnt = 1/(1+cnt).
// Sorted order makes the conv's xin access sweep node space monotonically.
__global__ __launch_bounds__(256) void sortdeg_kernel(
    const unsigned* __restrict__ rec, const int* __restrict__ bbase,
    const float* __restrict__ pos,
    unsigned* __restrict__ rec2, f16* __restrict__ wrec,
    float* __restrict__ dinv, float* __restrict__ rcnt, int N, int NSL)
{
    __shared__ float posL[BN * 3];
    __shared__ float ws[BN];
    __shared__ int cs[BN];
    __shared__ int hcnt[MAXSL];
    __shared__ int hoff[MAXSL];
    int t = threadIdx.x;
    int b = blockIdx.x;
    int nb0 = b << BK;
    for (int i = t; i < MAXSL; i += 256) hcnt[i] = 0;
    for (int i = t; i < BN; i += 256) {
        int n = nb0 + i;
        float px = 0, py = 0, pz = 0;
        if (n < N) {
            px = pos[3 * (size_t)n + 0];
            py = pos[3 * (size_t)n + 1];
            pz = pos[3 * (size_t)n + 2];
        }
        posL[i * 3 + 0] = px; posL[i * 3 + 1] = py; posL[i * 3 + 2] = pz;
        ws[i] = 0.0f; cs[i] = 0;
    }
    __syncthreads();
    int rb = bbase[b], re = bbase[b + 1];
    for (int j = rb + t; j < re; j += 256)
        atomicAdd(&hcnt[(rec[j] >> BK) >> SLK], 1);
    __syncthreads();
    if (t == 0) {
        int run = rb;
        for (int s2 = 0; s2 < NSL; s2++) { hoff[s2] = run; run += hcnt[s2]; }
    }
    __syncthreads();
    for (int i = t; i < MAXSL; i += 256) hcnt[i] = 0;   // reuse as cursors
    __syncthreads();
    for (int j = rb + t; j < re; j += 256) {
        unsigned r = rec[j];
        int s = r >> BK;
        int dl = r & (BN - 1);
        int sl = s >> SLK;
        float dx = posL[dl * 3 + 0] - pos[3 * (size_t)s + 0];
        float dy = posL[dl * 3 + 1] - pos[3 * (size_t)s + 1];
        float dz = posL[dl * 3 + 2] - pos[3 * (size_t)s + 2];
        float w = sqrtf(fmaf(dx, dx, fmaf(dy, dy, dz * dz)));
        int p = hoff[sl] + atomicAdd(&hcnt[sl], 1);
        rec2[p] = r;
        wrec[p] = (f16)w;
        atomicAdd(&ws[dl], w);
        atomicAdd(&cs[dl], 1);
    }
    __syncthreads();
    for (int i = t; i < BN; i += 256) {
        int n = nb0 + i;
        if (n < N) {
            dinv[n] = rsqrtf(1.0f + ws[i]);
            rcnt[n] = 1.0f / (float)(1 + cs[i]);
        }
    }
}

// x0 = sp(pos@Wi+bi); xwA = fp16( dinv[n] * (x0 @ W_g1) )  (pre-scaled by dinv[src])
__global__ __launch_bounds__(256) void node_init(
    const float* __restrict__ pos,
    const float* __restrict__ W_init, const float* __restrict__ b_init,
    const float* __restrict__ W_g1, const float* __restrict__ dinv,
    f16* __restrict__ xw, int N)
{
    __shared__ float sWi[ND * EM];
    __shared__ float sbi[EM];
    __shared__ float sW1[EM * EM];
    int t = threadIdx.x;
    if (t < ND * EM) sWi[t] = W_init[t];
    if (t < EM)      sbi[t] = b_init[t];
    sW1[t] = W_g1[t];
    __syncthreads();

    int n = blockIdx.x * 256 + t;
    if (n >= N) return;

    float p0 = pos[3 * (size_t)n + 0];
    float p1 = pos[3 * (size_t)n + 1];
    float p2 = pos[3 * (size_t)n + 2];

    float x0[EM];
#pragma unroll
    for (int j = 0; j < EM; j++) {
        float h = fmaf(p0, sWi[0 * EM + j],
                  fmaf(p1, sWi[1 * EM + j],
                  fmaf(p2, sWi[2 * EM + j], sbi[j])));
        x0[j] = sp(h);
    }
    float di = dinv[n];
    f16x8 h0, h1;
#pragma unroll
    for (int k = 0; k < EM; k++) {
        float a = 0.0f;
#pragma unroll
        for (int j = 0; j < EM; j++) a = fmaf(x0[j], sW1[j * EM + k], a);
        float v = a * di;
        if (k < 8) h0[k] = (f16)v; else h1[k - 8] = (f16)v;
    }
    f16x8* xo = (f16x8*)(xw + (size_t)n * EM);
    xo[0] = h0; xo[1] = h1;
}

// Fused per-bucket conv, records pre-sorted by src micro-slice.
// All 1954 blocks are co-resident (8/CU); sorted order makes every block sweep
// xin (16 MB fp16) monotonically -> each XCD's L2 holds the hot window.
// xin pre-scaled by dinv[src]; msg = (wrec*dinv[d]) * xin[s][c].
// mode 1: xout = fp16(dinv * (sp(mean+bias) @ W));  mode 2: fused heads.
__global__ __launch_bounds__(256, 8) void conv_kernel(
    const unsigned* __restrict__ rec2, const f16* __restrict__ wrec,
    const int* __restrict__ bbase,
    const float* __restrict__ dinv, const float* __restrict__ rcnt,
    const f16* __restrict__ xin,
    const float* __restrict__ bias, const float* __restrict__ W,
    const float* __restrict__ W_p1, const float* __restrict__ b_p1,
    const float* __restrict__ W_p2, const float* __restrict__ b_p2,
    const float* __restrict__ sig,
    f16* __restrict__ xoutH, float* __restrict__ outF, int N, int mode)
{
    __shared__ float acc[BN * ACCP];    // 17.4 KB
    __shared__ float dinvL[BN];
    __shared__ float sW[EM * EM];       // W (mode1) or W_p1 (mode2)
    __shared__ float sb[EM];
    __shared__ float sbp1[EM];
    __shared__ float sP2[EM * ND];
    __shared__ float sbp2[ND];

    int t = threadIdx.x;
    int b = blockIdx.x;
    int nb0 = b << BK;
    if (mode == 1) {
        sW[t] = W[t];
    } else {
        sW[t] = W_p1[t];
        if (t < EM)      sbp1[t] = b_p1[t];
        if (t < EM * ND) sP2[t] = W_p2[t];
        if (t < ND)      sbp2[t] = b_p2[t];
    }
    if (t < EM) sb[t] = bias[t];
    for (int i = t; i < BN; i += 256) {
        int n = nb0 + i;
        dinvL[i] = (n < N) ? dinv[n] : 0.0f;
    }
    for (int i = t; i < BN * ACCP; i += 256) acc[i] = 0.0f;
    __syncthreads();

    int rb = bbase[b], re = bbase[b + 1];
    int sub = t >> 4, c = t & 15;
    int j = rb + sub;
    // unrolled-by-8: 8 independent xin lines in flight per thread-slot
    for (; j + 112 < re; j += 128) {
        unsigned r[8]; float wv[8];
#pragma unroll
        for (int u = 0; u < 8; u++) { r[u] = rec2[j + 16 * u]; wv[u] = (float)wrec[j + 16 * u]; }
        float xv[8];
#pragma unroll
        for (int u = 0; u < 8; u++) xv[u] = (float)xin[((size_t)(r[u] >> BK) << 4) + c];
#pragma unroll
        for (int u = 0; u < 8; u++) {
            int dl = r[u] & (BN - 1);
            atomicAdd(&acc[dl * ACCP + c], wv[u] * dinvL[dl] * xv[u]);
        }
    }
    for (; j < re; j += 16) {
        unsigned r = rec2[j];
        float w = (float)wrec[j];
        int dl = r & (BN - 1);
        float xv = (float)xin[((size_t)(r >> BK) << 4) + c];
        atomicAdd(&acc[dl * ACCP + c], w * dinvL[dl] * xv);
    }
    __syncthreads();

    // fused epilogue
    int g = t >> 4;
    for (int i = g; i < BN; i += 16) {
        int n = nb0 + i;
        float xv = 0.0f;
        if (n < N) {
            float self = dinvL[i] * (float)xin[((size_t)n << 4) + c];
            xv = sp(fmaf(acc[i * ACCP + c] + self, rcnt[n], sb[c]));
        }
        acc[i * ACCP + c] = xv;   // same-wave 16-lane group: write then read (lockstep)
        if (n < N) {
            if (mode == 1) {
                float o = 0.0f;
#pragma unroll
                for (int jj = 0; jj < EM; jj++)
                    o = fmaf(acc[i * ACCP + jj], sW[jj * EM + c], o);
                xoutH[((size_t)n << 4) + c] = (f16)(dinvL[i] * o);
            } else {
                float a = sbp1[c];
#pragma unroll
                for (int jj = 0; jj < EM; jj++)
                    a = fmaf(acc[i * ACCP + jj], sW[jj * EM + c], a);
                float y = sp(a);
                acc[i * ACCP + c] = y;   // lockstep again
                if (c < ND) {
                    float o = sbp2[c];
#pragma unroll
                    for (int jj = 0; jj < EM; jj++)
                        o = fmaf(acc[i * ACCP + jj], sP2[jj * ND + c], o);
                    outF[(size_t)n * ND + c] = o / sig[n];
                }
            }
        }
    }
}

extern "C" void kernel_launch(void* const* d_in, const int* in_sizes, int n_in,
                              void* d_out, int out_size, void* d_ws, size_t ws_size,
                              hipStream_t stream) {
    const float* pos    = (const float*)d_in[0];
    const float* sig    = (const float*)d_in[1];
    const int*   ei     = (const int*)d_in[2];
    const float* W_init = (const float*)d_in[4];
    const float* b_init = (const float*)d_in[5];
    const float* W_g1   = (const float*)d_in[6];
    const float* b_g1   = (const float*)d_in[7];
    const float* W_g2   = (const float*)d_in[8];
    const float* b_g2   = (const float*)d_in[9];
    const float* W_p1   = (const float*)d_in[10];
    const float* b_p1   = (const float*)d_in[11];
    const float* W_p2   = (const float*)d_in[12];
    const float* b_p2   = (const float*)d_in[13];
    float* out = (float*)d_out;

    int N = in_sizes[0] / ND;
    int E = in_sizes[2] / 2;
    int NB = (N + BN - 1) >> BK;          // 1954 for N=500000
    int NSL = (N + (1 << SLK) - 1) >> SLK; // 123 micro-slices
    size_t Ns = (size_t)N, Es = (size_t)E;

    // ws layout, 64B-aligned chunks.
    char* wsb = (char*)d_ws;
    size_t cur = 0;
    auto alloc = [&](size_t bytes) -> void* {
        void* p = wsb + cur; cur += (bytes + 63) & ~(size_t)63; return p;
    };
    unsigned* rec  = (unsigned*)alloc(Es * 4);
    unsigned* rec2 = (unsigned*)alloc(Es * 4);
    f16* wrec = (f16*)alloc(Es * 2);
    int* bbase = (int*)alloc(((size_t)NB + 1) * 4);
    int* gcur  = (int*)alloc((size_t)NB * 4);
    float* dinv = (float*)alloc(Ns * 4);
    float* rcnt = (float*)alloc(Ns * 4);
    f16* xwA = (f16*)alloc(Ns * EM * 2);
    f16* xwB = (f16*)alloc(Ns * EM * 2);

    int nbN = (N + 255) / 256;
    int nbE4 = (E + 4095) / 4096;

    zero_gcur<<<(NB + 1023) / 1024, 1024, 0, stream>>>(gcur, NB);
    hist_kernel<<<nbE4, 256, 0, stream>>>(ei, gcur, E, NB);
    scan_kernel<<<1, 1024, 0, stream>>>(gcur, bbase, NB, E);
    pass2_kernel<<<nbE4, 256, 0, stream>>>(ei, bbase, gcur, rec, E, NB);
    sortdeg_kernel<<<NB, 256, 0, stream>>>(rec, bbase, pos, rec2, wrec,
                                           dinv, rcnt, N, NSL);
    node_init<<<nbN, 256, 0, stream>>>(pos, W_init, b_init, W_g1, dinv, xwA, N);
    conv_kernel<<<NB, 256, 0, stream>>>(rec2, wrec, bbase, dinv, rcnt, xwA,
                                        b_g1, W_g2, W_p1, b_p1, W_p2, b_p2, sig,
                                        xwB, out, N, 1);
    conv_kernel<<<NB, 256, 0, stream>>>(rec2, wrec, bbase, dinv, rcnt, xwB,
                                        b_g2, W_g2, W_p1, b_p1, W_p2, b_p2, sig,
                                        xwB, out, N, 2);
}